// Round 11
// baseline (156.174 us; speedup 1.0000x reference)
//
#include <hip/hip_runtime.h>
#include <hip/hip_bf16.h>

#define NS_TOT 2000
#define NA 1000
#define NI 5
#define NH 32
#define SHALF 1000                 // structs per block (two blocks per atom)

typedef __attribute__((ext_vector_type(2)))  float f32x2;
typedef __attribute__((ext_vector_type(8)))  short short8;   // 8 bf16 = 4 VGPR
typedef __attribute__((ext_vector_type(16))) float f32x16;   // MFMA 32x32 acc

struct f4pair  { f32x2 a, b; };
struct accpair { f32x2 p[8]; };

// Scalar Pade[5/4] tanh (same polynomial as passing R9): ~1e-3 max err.
__device__ __forceinline__ float fast_tanh(float x) {
    float z = x * x;
    float n = fmaf(z + 105.0f, z, 945.0f);
    float d = fmaf(fmaf(z, 15.0f, 420.0f), z, 945.0f);
    float r = __builtin_amdgcn_rcpf(d);
    float tv = x * n * r;
    return __builtin_amdgcn_fmed3f(tv, -1.0f, 1.0f);
}
// R9's packed form for the epilogue (kept identical; it passed at 63us).
__device__ __forceinline__ f32x2 tanh_pk(f32x2 X) {
    f32x2 z = X * X;
    f32x2 n = (z + 105.0f) * z + 945.0f;
    f32x2 d = (z * 15.0f + 420.0f) * z + 945.0f;
    f32x2 r;
    r.x = __builtin_amdgcn_rcpf(d.x);
    r.y = __builtin_amdgcn_rcpf(d.y);
    f32x2 t = X * n * r;
    t.x = __builtin_amdgcn_fmed3f(t.x, -1.0f, 1.0f);
    t.y = __builtin_amdgcn_fmed3f(t.y, -1.0f, 1.0f);
    return t;
}

__device__ __forceinline__ unsigned short f2bf_rne(float x) {
    unsigned u = __float_as_uint(x);
    unsigned r = u + 0x7FFFu + ((u >> 16) & 1u);
    return (unsigned short)(r >> 16);
}
__device__ __forceinline__ unsigned pack2(float a, float b) {
    __hip_bfloat162 p = __float22bfloat162_rn(make_float2(a, b));
    unsigned u; __builtin_memcpy(&u, &p, 4); return u;
}

// R11: L1 as MFMA with g supplied DIRECTLY as the B-fragment (K padded 5->16:
// half-1 lanes hold the zero padding, so no transpose is needed; bias b1
// folded into K-slot 5 with B[5][n]=1.0). The L1 C-layout output is converted
// to the L2 B-fragment in-register: owner(m)=(m>>2)&1, r(m)=(m&3)+4*(m>>3)
// -> 8 shfl_xor(32) + 16 selects per 32-struct tile. This deletes the
// per-iteration pack->LDS->barrier->LDS->frag chain and L1's 160 v_fmac.
__global__ __attribute__((amdgpu_flat_work_group_size(256, 256),
                          amdgpu_waves_per_eu(4, 8)))
void mlp_mfma(
    const float* __restrict__ g,
    const float* __restrict__ W1, const float* __restrict__ b1,
    const float* __restrict__ W2, const float* __restrict__ b2,
    const float* __restrict__ W3, const float* __restrict__ b3,
    float* __restrict__ out)
{
    const int bid   = blockIdx.x;
    const int araw  = bid % NA;
    const int chunk = bid / NA;
    const int a = (araw >> 3) + 125 * (araw & 7);   // same-XCD atom swizzle
    const int t = threadIdx.x;
    const int lane = t & 63, wid = t >> 6;
    const int l31 = lane & 31, half = lane >> 5;

    const int sbase_blk = chunk * SHALF;
    const int send      = sbase_blk + SHALF;

    __shared__ __align__(16) unsigned short sW2T[NH * NH];  // W2^T bf16 [m][k]
    __shared__ __align__(16) unsigned short sW1T[NH * 8];   // [m]{W1[0..4][m],b1[m],0,0}
    __shared__ __align__(16) float sB2[NH];
    __shared__ __align__(16) float sW3[NH];

    for (int idx = t; idx < NH * NH; idx += 256) {
        const int i = idx >> 5, j = idx & 31;
        sW2T[j * NH + i] = f2bf_rne(W2[(size_t)a * NH * NH + idx]);
    }
    if (t < NH) {
        sB2[t] = b2[a * NH + t];
        sW3[t] = W3[a * NH + t];
        const int m = t;
        #pragma unroll
        for (int i = 0; i < NI; ++i)
            sW1T[m * 8 + i] = f2bf_rne(W1[(size_t)a * NI * NH + i * NH + m]);
        sW1T[m * 8 + 5] = f2bf_rne(b1[a * NH + m]);
        sW1T[m * 8 + 6] = 0;
        sW1T[m * 8 + 7] = 0;
    }
    __syncthreads();

    // persistent fragments
    const short8 zero8 = {0,0,0,0,0,0,0,0};
    const short8 w1ld = __builtin_bit_cast(short8, *(const uint4*)(sW1T + l31 * 8));
    const short8 afl1 = half ? zero8 : w1ld;   // A[m][k]: half1 = K-pad zeros
    const short8 af0 = __builtin_bit_cast(short8, *(const uint4*)(sW2T + l31 * NH + half * 8));
    const short8 af1 = __builtin_bit_cast(short8, *(const uint4*)(sW2T + l31 * NH + 16 + half * 8));
    const float4 b2q0 = ((const float4*)sB2)[0 + half];
    const float4 b2q1 = ((const float4*)sB2)[2 + half];
    const float4 b2q2 = ((const float4*)sB2)[4 + half];
    const float4 b2q3 = ((const float4*)sB2)[6 + half];
    const float4 w3q0 = ((const float4*)sW3)[0 + half];
    const float4 w3q1 = ((const float4*)sW3)[2 + half];
    const float4 w3q2 = ((const float4*)sW3)[4 + half];
    const float4 w3q3 = ((const float4*)sW3)[6 + half];
    const float bias3 = b3[a];
    const f4pair w3p0 = __builtin_bit_cast(f4pair, w3q0);
    const f4pair w3p1 = __builtin_bit_cast(f4pair, w3q1);
    const f4pair w3p2 = __builtin_bit_cast(f4pair, w3q2);
    const f4pair w3p3 = __builtin_bit_cast(f4pair, w3q3);
    const f32x16 zacc = {0,0,0,0,0,0,0,0,0,0,0,0,0,0,0,0};

    for (int it = 0; it < 4; ++it) {
        const int base = sbase_blk + it * 256 + wid * 64;
        const int s = base + lane;
        const int sl = (s < send) ? s : (send - 1);

        const float* gp = g + ((size_t)sl * NA + a) * NI;
        const float x0g = gp[0], x1g = gp[1], x2g = gp[2], x3g = gp[3], x4g = gp[4];

        // ---- build g B-fragments (K=16, slots: g0..g4, 1.0(bias), 0, 0) ----
        const unsigned gp01 = pack2(x0g, x1g);
        const unsigned gp23 = pack2(x2g, x3g);
        const unsigned gp45 = pack2(x4g, 1.0f);
        // tile1 (structs base+32..63): their g lives on half-1 lanes -> swap
        const unsigned q01 = __shfl_xor((int)gp01, 32);
        const unsigned q23 = __shfl_xor((int)gp23, 32);
        const unsigned q45 = __shfl_xor((int)gp45, 32);
        const unsigned zu = 0;
        uint4 bu0 = make_uint4(half ? zu : gp01, half ? zu : gp23,
                               half ? zu : gp45, zu);
        uint4 bu1 = make_uint4(half ? zu : q01, half ? zu : q23,
                               half ? zu : q45, zu);
        const short8 gb0 = __builtin_bit_cast(short8, bu0);
        const short8 gb1 = __builtin_bit_cast(short8, bu1);

        // ---- layer 1 via MFMA (bias folded in) ----
        f32x16 d0 = __builtin_amdgcn_mfma_f32_32x32x16_bf16(afl1, gb0, zacc, 0, 0, 0);
        f32x16 d1 = __builtin_amdgcn_mfma_f32_32x32x16_bf16(afl1, gb1, zacc, 0, 0, 0);

        // ---- tanh + C-layout -> B-fragment permute, per tile ----
        short8 bk0_0, bk1_0, bk0_1, bk1_1;
        #define TILE_CONV(DD, BK0, BK1) { \
            float th[16]; \
            th[0]=fast_tanh(DD[0]);   th[1]=fast_tanh(DD[1]); \
            th[2]=fast_tanh(DD[2]);   th[3]=fast_tanh(DD[3]); \
            th[4]=fast_tanh(DD[4]);   th[5]=fast_tanh(DD[5]); \
            th[6]=fast_tanh(DD[6]);   th[7]=fast_tanh(DD[7]); \
            th[8]=fast_tanh(DD[8]);   th[9]=fast_tanh(DD[9]); \
            th[10]=fast_tanh(DD[10]); th[11]=fast_tanh(DD[11]); \
            th[12]=fast_tanh(DD[12]); th[13]=fast_tanh(DD[13]); \
            th[14]=fast_tanh(DD[14]); th[15]=fast_tanh(DD[15]); \
            float rc[8]; \
            rc[0] = __shfl_xor(half ? th[0]  : th[4],  32); \
            rc[1] = __shfl_xor(half ? th[1]  : th[5],  32); \
            rc[2] = __shfl_xor(half ? th[2]  : th[6],  32); \
            rc[3] = __shfl_xor(half ? th[3]  : th[7],  32); \
            rc[4] = __shfl_xor(half ? th[8]  : th[12], 32); \
            rc[5] = __shfl_xor(half ? th[9]  : th[13], 32); \
            rc[6] = __shfl_xor(half ? th[10] : th[14], 32); \
            rc[7] = __shfl_xor(half ? th[11] : th[15], 32); \
            float e0[8], e1[8]; \
            e0[0] = half ? rc[0] : th[0]; e0[1] = half ? rc[1] : th[1]; \
            e0[2] = half ? rc[2] : th[2]; e0[3] = half ? rc[3] : th[3]; \
            e0[4] = half ? th[4] : rc[0]; e0[5] = half ? th[5] : rc[1]; \
            e0[6] = half ? th[6] : rc[2]; e0[7] = half ? th[7] : rc[3]; \
            e1[0] = half ? rc[4] : th[8];  e1[1] = half ? rc[5] : th[9]; \
            e1[2] = half ? rc[6] : th[10]; e1[3] = half ? rc[7] : th[11]; \
            e1[4] = half ? th[12] : rc[4]; e1[5] = half ? th[13] : rc[5]; \
            e1[6] = half ? th[14] : rc[6]; e1[7] = half ? th[15] : rc[7]; \
            uint4 u0 = make_uint4(pack2(e0[0],e0[1]), pack2(e0[2],e0[3]), \
                                  pack2(e0[4],e0[5]), pack2(e0[6],e0[7])); \
            uint4 u1 = make_uint4(pack2(e1[0],e1[1]), pack2(e1[2],e1[3]), \
                                  pack2(e1[4],e1[5]), pack2(e1[6],e1[7])); \
            BK0 = __builtin_bit_cast(short8, u0); \
            BK1 = __builtin_bit_cast(short8, u1); }
        TILE_CONV(d0, bk0_0, bk1_0)
        TILE_CONV(d1, bk0_1, bk1_1)
        #undef TILE_CONV

        // ---- layer 2 MFMA ----
        f32x16 acc0 = {b2q0.x, b2q0.y, b2q0.z, b2q0.w,
                       b2q1.x, b2q1.y, b2q1.z, b2q1.w,
                       b2q2.x, b2q2.y, b2q2.z, b2q2.w,
                       b2q3.x, b2q3.y, b2q3.z, b2q3.w};
        f32x16 acc1 = acc0;
        acc0 = __builtin_amdgcn_mfma_f32_32x32x16_bf16(af0, bk0_0, acc0, 0, 0, 0);
        acc0 = __builtin_amdgcn_mfma_f32_32x32x16_bf16(af1, bk1_0, acc0, 0, 0, 0);
        acc1 = __builtin_amdgcn_mfma_f32_32x32x16_bf16(af0, bk0_1, acc1, 0, 0, 0);
        acc1 = __builtin_amdgcn_mfma_f32_32x32x16_bf16(af1, bk1_1, acc1, 0, 0, 0);

        // ---- epilogue: packed tanh + packed layer-3 dot (identical to R9) ----
        const accpair ap0 = __builtin_bit_cast(accpair, acc0);
        const accpair ap1 = __builtin_bit_cast(accpair, acc1);
        f32x2 p0 = {0.f, 0.f}, p1 = {0.f, 0.f};
        #define EPP(r, wpair) { \
            p0 += tanh_pk(ap0.p[r]) * (wpair); \
            p1 += tanh_pk(ap1.p[r]) * (wpair); }
        EPP(0, w3p0.a) EPP(1, w3p0.b)
        EPP(2, w3p1.a) EPP(3, w3p1.b)
        EPP(4, w3p2.a) EPP(5, w3p2.b)
        EPP(6, w3p3.a) EPP(7, w3p3.b)
        #undef EPP
        float e0 = p0.x + p0.y;
        float e1 = p1.x + p1.y;
        e0 += __shfl_xor(e0, 32);
        e1 += __shfl_xor(e1, 32);

        if (lane < 32) {
            const int st0 = base + l31;
            const int st1 = base + 32 + l31;
            if (st0 < send) out[(size_t)st0 * NA + a] = e0 + bias3;
            if (st1 < send) out[(size_t)st1 * NA + a] = e1 + bias3;
        }
    }
}

extern "C" void kernel_launch(void* const* d_in, const int* in_sizes, int n_in,
                              void* d_out, int out_size, void* d_ws, size_t ws_size,
                              hipStream_t stream) {
    const float* g  = (const float*)d_in[0];
    const float* W1 = (const float*)d_in[1];
    const float* b1 = (const float*)d_in[2];
    const float* W2 = (const float*)d_in[3];
    const float* b2 = (const float*)d_in[4];
    const float* W3 = (const float*)d_in[5];
    const float* b3 = (const float*)d_in[6];
    float* out = (float*)d_out;
    mlp_mfma<<<dim3(NA * 2), dim3(256), 0, stream>>>(g, W1, b1, W2, b2, W3, b3, out);
}

// Round 12
// 126.917 us; speedup vs baseline: 1.2305x; 1.2305x over previous
//
#include <hip/hip_runtime.h>
#include <hip/hip_bf16.h>

#define NS_TOT 2000
#define NA 1000
#define NI 5
#define NH 32
#define SHALF 1000                 // structs per block (two blocks per atom)

typedef __attribute__((ext_vector_type(2)))  float f32x2;
typedef __attribute__((ext_vector_type(8)))  short short8;   // 8 bf16 = 4 VGPR
typedef __attribute__((ext_vector_type(16))) float f32x16;   // MFMA 32x32 acc

struct f4pair  { f32x2 a, b; };
struct accpair { f32x2 p[8]; };

// Scalar Pade[5/4] tanh (same polynomial as passing R9): ~1e-3 max err.
__device__ __forceinline__ float fast_tanh(float x) {
    float z = x * x;
    float n = fmaf(z + 105.0f, z, 945.0f);
    float d = fmaf(fmaf(z, 15.0f, 420.0f), z, 945.0f);
    float r = __builtin_amdgcn_rcpf(d);
    float tv = x * n * r;
    return __builtin_amdgcn_fmed3f(tv, -1.0f, 1.0f);
}
// R9's packed form for the epilogue.
__device__ __forceinline__ f32x2 tanh_pk(f32x2 X) {
    f32x2 z = X * X;
    f32x2 n = (z + 105.0f) * z + 945.0f;
    f32x2 d = (z * 15.0f + 420.0f) * z + 945.0f;
    f32x2 r;
    r.x = __builtin_amdgcn_rcpf(d.x);
    r.y = __builtin_amdgcn_rcpf(d.y);
    f32x2 t = X * n * r;
    t.x = __builtin_amdgcn_fmed3f(t.x, -1.0f, 1.0f);
    t.y = __builtin_amdgcn_fmed3f(t.y, -1.0f, 1.0f);
    return t;
}

__device__ __forceinline__ unsigned short f2bf_rne(float x) {
    unsigned u = __float_as_uint(x);
    unsigned r = u + 0x7FFFu + ((u >> 16) & 1u);
    return (unsigned short)(r >> 16);
}
__device__ __forceinline__ unsigned pack2(float a, float b) {
    __hip_bfloat162 p = __float22bfloat162_rn(make_float2(a, b));
    unsigned u; __builtin_memcpy(&u, &p, 4); return u;
}

// R11 structure (L1 via MFMA, g as direct B-fragment, in-register C->B
// permute -- layout PROVEN by R11's unchanged absmax). R11's regression was
// the occupancy attribute: waves_per_eu(4,8) let the allocator target 8
// waves/EU (64-VGPR budget) while this structure's live set is ~100
// (d0,d1 + acc0,acc1 + 3 A-fragments + w3/b2 quads) -> 62 MB of scratch
// spills, VALUBusy 43%. waves_per_eu(4,4) = hard 128-VGPR budget, no spill
// (the R5 lesson: pin occupancy EXACTLY where the live set fits).
__global__ __attribute__((amdgpu_flat_work_group_size(256, 256),
                          amdgpu_waves_per_eu(4, 4)))
void mlp_mfma(
    const float* __restrict__ g,
    const float* __restrict__ W1, const float* __restrict__ b1,
    const float* __restrict__ W2, const float* __restrict__ b2,
    const float* __restrict__ W3, const float* __restrict__ b3,
    float* __restrict__ out)
{
    const int bid   = blockIdx.x;
    const int araw  = bid % NA;
    const int chunk = bid / NA;
    const int a = (araw >> 3) + 125 * (araw & 7);   // same-XCD atom swizzle
    const int t = threadIdx.x;
    const int lane = t & 63, wid = t >> 6;
    const int l31 = lane & 31, half = lane >> 5;

    const int sbase_blk = chunk * SHALF;
    const int send      = sbase_blk + SHALF;

    __shared__ __align__(16) unsigned short sW2T[NH * NH];  // W2^T bf16 [m][k]
    __shared__ __align__(16) unsigned short sW1T[NH * 8];   // [m]{W1[0..4][m],b1[m],0,0}
    __shared__ __align__(16) float sB2[NH];
    __shared__ __align__(16) float sW3[NH];

    for (int idx = t; idx < NH * NH; idx += 256) {
        const int i = idx >> 5, j = idx & 31;
        sW2T[j * NH + i] = f2bf_rne(W2[(size_t)a * NH * NH + idx]);
    }
    if (t < NH) {
        sB2[t] = b2[a * NH + t];
        sW3[t] = W3[a * NH + t];
        const int m = t;
        #pragma unroll
        for (int i = 0; i < NI; ++i)
            sW1T[m * 8 + i] = f2bf_rne(W1[(size_t)a * NI * NH + i * NH + m]);
        sW1T[m * 8 + 5] = f2bf_rne(b1[a * NH + m]);
        sW1T[m * 8 + 6] = 0;
        sW1T[m * 8 + 7] = 0;
    }
    __syncthreads();

    // persistent fragments
    const short8 zero8 = {0,0,0,0,0,0,0,0};
    const short8 w1ld = __builtin_bit_cast(short8, *(const uint4*)(sW1T + l31 * 8));
    const short8 afl1 = half ? zero8 : w1ld;   // A[m][k]: half1 = K-pad zeros
    const short8 af0 = __builtin_bit_cast(short8, *(const uint4*)(sW2T + l31 * NH + half * 8));
    const short8 af1 = __builtin_bit_cast(short8, *(const uint4*)(sW2T + l31 * NH + 16 + half * 8));
    const float4 b2q0 = ((const float4*)sB2)[0 + half];
    const float4 b2q1 = ((const float4*)sB2)[2 + half];
    const float4 b2q2 = ((const float4*)sB2)[4 + half];
    const float4 b2q3 = ((const float4*)sB2)[6 + half];
    const float4 w3q0 = ((const float4*)sW3)[0 + half];
    const float4 w3q1 = ((const float4*)sW3)[2 + half];
    const float4 w3q2 = ((const float4*)sW3)[4 + half];
    const float4 w3q3 = ((const float4*)sW3)[6 + half];
    const float bias3 = b3[a];
    const f4pair w3p0 = __builtin_bit_cast(f4pair, w3q0);
    const f4pair w3p1 = __builtin_bit_cast(f4pair, w3q1);
    const f4pair w3p2 = __builtin_bit_cast(f4pair, w3q2);
    const f4pair w3p3 = __builtin_bit_cast(f4pair, w3q3);
    const f32x16 zacc = {0,0,0,0,0,0,0,0,0,0,0,0,0,0,0,0};

    for (int it = 0; it < 4; ++it) {
        const int base = sbase_blk + it * 256 + wid * 64;
        const int s = base + lane;
        const int sl = (s < send) ? s : (send - 1);

        const float* gp = g + ((size_t)sl * NA + a) * NI;
        const float x0g = gp[0], x1g = gp[1], x2g = gp[2], x3g = gp[3], x4g = gp[4];

        // ---- build g B-fragments (K=16, slots: g0..g4, 1.0(bias), 0, 0) ----
        const unsigned gp01 = pack2(x0g, x1g);
        const unsigned gp23 = pack2(x2g, x3g);
        const unsigned gp45 = pack2(x4g, 1.0f);
        // tile1 (structs base+32..63): their g lives on half-1 lanes -> swap
        const unsigned q01 = __shfl_xor((int)gp01, 32);
        const unsigned q23 = __shfl_xor((int)gp23, 32);
        const unsigned q45 = __shfl_xor((int)gp45, 32);
        const unsigned zu = 0;
        uint4 bu0 = make_uint4(half ? zu : gp01, half ? zu : gp23,
                               half ? zu : gp45, zu);
        uint4 bu1 = make_uint4(half ? zu : q01, half ? zu : q23,
                               half ? zu : q45, zu);
        const short8 gb0 = __builtin_bit_cast(short8, bu0);
        const short8 gb1 = __builtin_bit_cast(short8, bu1);

        // ---- layer 1 via MFMA (bias folded in) ----
        f32x16 d0 = __builtin_amdgcn_mfma_f32_32x32x16_bf16(afl1, gb0, zacc, 0, 0, 0);
        f32x16 d1 = __builtin_amdgcn_mfma_f32_32x32x16_bf16(afl1, gb1, zacc, 0, 0, 0);

        // ---- tanh + C-layout -> B-fragment permute, per tile ----
        short8 bk0_0, bk1_0, bk0_1, bk1_1;
        #define TILE_CONV(DD, BK0, BK1) { \
            float th[16]; \
            th[0]=fast_tanh(DD[0]);   th[1]=fast_tanh(DD[1]); \
            th[2]=fast_tanh(DD[2]);   th[3]=fast_tanh(DD[3]); \
            th[4]=fast_tanh(DD[4]);   th[5]=fast_tanh(DD[5]); \
            th[6]=fast_tanh(DD[6]);   th[7]=fast_tanh(DD[7]); \
            th[8]=fast_tanh(DD[8]);   th[9]=fast_tanh(DD[9]); \
            th[10]=fast_tanh(DD[10]); th[11]=fast_tanh(DD[11]); \
            th[12]=fast_tanh(DD[12]); th[13]=fast_tanh(DD[13]); \
            th[14]=fast_tanh(DD[14]); th[15]=fast_tanh(DD[15]); \
            float rc[8]; \
            rc[0] = __shfl_xor(half ? th[0]  : th[4],  32); \
            rc[1] = __shfl_xor(half ? th[1]  : th[5],  32); \
            rc[2] = __shfl_xor(half ? th[2]  : th[6],  32); \
            rc[3] = __shfl_xor(half ? th[3]  : th[7],  32); \
            rc[4] = __shfl_xor(half ? th[8]  : th[12], 32); \
            rc[5] = __shfl_xor(half ? th[9]  : th[13], 32); \
            rc[6] = __shfl_xor(half ? th[10] : th[14], 32); \
            rc[7] = __shfl_xor(half ? th[11] : th[15], 32); \
            float e0[8], e1[8]; \
            e0[0] = half ? rc[0] : th[0]; e0[1] = half ? rc[1] : th[1]; \
            e0[2] = half ? rc[2] : th[2]; e0[3] = half ? rc[3] : th[3]; \
            e0[4] = half ? th[4] : rc[0]; e0[5] = half ? th[5] : rc[1]; \
            e0[6] = half ? th[6] : rc[2]; e0[7] = half ? th[7] : rc[3]; \
            e1[0] = half ? rc[4] : th[8];  e1[1] = half ? rc[5] : th[9]; \
            e1[2] = half ? rc[6] : th[10]; e1[3] = half ? rc[7] : th[11]; \
            e1[4] = half ? th[12] : rc[4]; e1[5] = half ? th[13] : rc[5]; \
            e1[6] = half ? th[14] : rc[6]; e1[7] = half ? th[15] : rc[7]; \
            uint4 u0 = make_uint4(pack2(e0[0],e0[1]), pack2(e0[2],e0[3]), \
                                  pack2(e0[4],e0[5]), pack2(e0[6],e0[7])); \
            uint4 u1 = make_uint4(pack2(e1[0],e1[1]), pack2(e1[2],e1[3]), \
                                  pack2(e1[4],e1[5]), pack2(e1[6],e1[7])); \
            BK0 = __builtin_bit_cast(short8, u0); \
            BK1 = __builtin_bit_cast(short8, u1); }
        TILE_CONV(d0, bk0_0, bk1_0)
        TILE_CONV(d1, bk0_1, bk1_1)
        #undef TILE_CONV

        // ---- layer 2 MFMA ----
        f32x16 acc0 = {b2q0.x, b2q0.y, b2q0.z, b2q0.w,
                       b2q1.x, b2q1.y, b2q1.z, b2q1.w,
                       b2q2.x, b2q2.y, b2q2.z, b2q2.w,
                       b2q3.x, b2q3.y, b2q3.z, b2q3.w};
        f32x16 acc1 = acc0;
        acc0 = __builtin_amdgcn_mfma_f32_32x32x16_bf16(af0, bk0_0, acc0, 0, 0, 0);
        acc0 = __builtin_amdgcn_mfma_f32_32x32x16_bf16(af1, bk1_0, acc0, 0, 0, 0);
        acc1 = __builtin_amdgcn_mfma_f32_32x32x16_bf16(af0, bk0_1, acc1, 0, 0, 0);
        acc1 = __builtin_amdgcn_mfma_f32_32x32x16_bf16(af1, bk1_1, acc1, 0, 0, 0);

        // ---- epilogue: packed tanh + packed layer-3 dot (identical to R9) ----
        const accpair ap0 = __builtin_bit_cast(accpair, acc0);
        const accpair ap1 = __builtin_bit_cast(accpair, acc1);
        f32x2 p0 = {0.f, 0.f}, p1 = {0.f, 0.f};
        #define EPP(r, wpair) { \
            p0 += tanh_pk(ap0.p[r]) * (wpair); \
            p1 += tanh_pk(ap1.p[r]) * (wpair); }
        EPP(0, w3p0.a) EPP(1, w3p0.b)
        EPP(2, w3p1.a) EPP(3, w3p1.b)
        EPP(4, w3p2.a) EPP(5, w3p2.b)
        EPP(6, w3p3.a) EPP(7, w3p3.b)
        #undef EPP
        float e0 = p0.x + p0.y;
        float e1 = p1.x + p1.y;
        e0 += __shfl_xor(e0, 32);
        e1 += __shfl_xor(e1, 32);

        if (lane < 32) {
            const int st0 = base + l31;
            const int st1 = base + 32 + l31;
            if (st0 < send) out[(size_t)st0 * NA + a] = e0 + bias3;
            if (st1 < send) out[(size_t)st1 * NA + a] = e1 + bias3;
        }
    }
}

extern "C" void kernel_launch(void* const* d_in, const int* in_sizes, int n_in,
                              void* d_out, int out_size, void* d_ws, size_t ws_size,
                              hipStream_t stream) {
    const float* g  = (const float*)d_in[0];
    const float* W1 = (const float*)d_in[1];
    const float* b1 = (const float*)d_in[2];
    const float* W2 = (const float*)d_in[3];
    const float* b2 = (const float*)d_in[4];
    const float* W3 = (const float*)d_in[5];
    const float* b3 = (const float*)d_in[6];
    float* out = (float*)d_out;
    mlp_mfma<<<dim3(NA * 2), dim3(256), 0, stream>>>(g, W1, b1, W2, b2, W3, b3, out);
}